// Round 12
// baseline (249.745 us; speedup 1.0000x reference)
//
#include <hip/hip_runtime.h>
#include <math.h>

// Sizes from the reference
#define B_SZ 4096
#define N_SZ 16
#define A_SZ 8
#define IN_DIM 128
#define OUT_DIM 128
#define D_OBS 128
#define ROW_OUT 136              // floats per output row = 34 float4

typedef float f32x4 __attribute__((ext_vector_type(4)));

// ws layout (floats): asrc[B*16] | adst[B*16] | sumz[B*16*8]  = 2.62 MB
#define WS_ASRC   0
#define WS_ADST   (B_SZ * 16)
#define WS_SUMZ   (B_SZ * 32)
#define WS_FLOATS (B_SZ * 32 + B_SZ * 128)

// ---------------------------------------------------------------------------
// Kernel 1: compute-only. One block per b. Folds W_attn@W_fc (v) in-block
// (W_fc is 64 KB, L2-resident across blocks -> ~free; removes the serial
// prep_v dispatch). Writes a_src/a_dst/sum_z to ws, w to out_w.
// ---------------------------------------------------------------------------
__global__ __launch_bounds__(256) void gat_compute(
    const float* __restrict__ h,        // [B,16,128]
    const float* __restrict__ pol,      // [B,16,8]
    const float* __restrict__ act,      // [B,16,8]
    const float* __restrict__ W_fc,     // [128,128]
    const float* __restrict__ W_attn,   // [1,256]
    float* __restrict__ ws,
    float* __restrict__ out_w)          // [B*16,16,1]
{
  const int b = blockIdx.x;
  const int tid = threadIdx.x;

  __shared__ float vsm[256];         // v_src[128] | v_dst[128]
  __shared__ float a_src_sm[16];
  __shared__ float a_dst_sm[16];
  __shared__ float w_sm[256];
  __shared__ float pol_sm[128];
  __shared__ float act_sm[128];

  // fold: vsm[tid] = sum_o W_fc[o, tid&127] * W_attn[(tid>>7)*128 + o]
  {
    const int col = tid & 127;
    const float* wa = W_attn + ((tid >> 7) << 7);
    float acc = 0.f;
    #pragma unroll 8
    for (int o = 0; o < OUT_DIM; ++o)
      acc += W_fc[o * IN_DIM + col] * wa[o];
    vsm[tid] = acc;
  }

  if (tid < 128) {
    pol_sm[tid] = pol[(size_t)b * 128 + tid];
    act_sm[tid] = act[(size_t)b * 128 + tid];
  }
  __syncthreads();   // vsm ready

  // phase 1: a_src/a_dst (16 lanes per row, 8 elems per lane)
  {
    const int l = tid & 15;
    const f32x4* hp = (const f32x4*)(h + (size_t)b * (N_SZ * IN_DIM));
    const f32x4 h0 = __builtin_nontemporal_load(&hp[tid * 2]);
    const f32x4 h1 = __builtin_nontemporal_load(&hp[tid * 2 + 1]);
    const f32x4* vs = (const f32x4*)vsm;
    const f32x4* vd = (const f32x4*)(vsm + 128);
    const f32x4 s0 = vs[l * 2], s1 = vs[l * 2 + 1];
    const f32x4 d0 = vd[l * 2], d1 = vd[l * 2 + 1];
    float s = h0.x * s0.x + h0.y * s0.y + h0.z * s0.z + h0.w * s0.w
            + h1.x * s1.x + h1.y * s1.y + h1.z * s1.z + h1.w * s1.w;
    float d = h0.x * d0.x + h0.y * d0.y + h0.z * d0.z + h0.w * d0.w
            + h1.x * d1.x + h1.y * d1.y + h1.z * d1.z + h1.w * d1.w;
    for (int m = 8; m >= 1; m >>= 1) {
      s += __shfl_xor(s, m, 16);
      d += __shfl_xor(d, m, 16);
    }
    if (l == 0) {
      a_src_sm[tid >> 4] = s;
      a_dst_sm[tid >> 4] = d;
    }
  }
  __syncthreads();

  // persist a_src/a_dst for the streaming kernel
  if (tid < 16)       ws[WS_ASRC + b * 16 + tid] = a_src_sm[tid];
  else if (tid < 32)  ws[WS_ADST + b * 16 + (tid - 16)] = a_dst_sm[tid - 16];

  // phase 2: w[i][j]
  {
    float e = a_src_sm[tid & 15] + a_dst_sm[tid >> 4];
    e = (e >= 0.f) ? e : 0.01f * e;
    const float wv = 1.f / (1.f + expf(-e));
    w_sm[tid] = wv;
    out_w[(size_t)b * 256 + tid] = wv;
  }
  __syncthreads();

  // phase 3a: sum_z[i][a] -> ws
  if (tid < 128) {
    const int i = tid >> 3, a = tid & 7;
    float s = 0.f;
    #pragma unroll
    for (int j = 0; j < N_SZ; ++j) {
      const float wv = w_sm[i * 16 + j];
      s += wv * act_sm[j * 8 + a] + (1.f - wv) * pol_sm[j * 8 + a];
    }
    ws[WS_SUMZ + b * 128 + tid] = s;
  }
}

// ---------------------------------------------------------------------------
// Kernel 2: fill-shaped dense-front writer of out0 with PLAIN (cached)
// stores — the untested cell of the {front-shape x store-type} matrix.
// Grid-stride over all 35,651,584 float4s; zero LDS, zero barriers.
// Plain stores let L2 aggregate full dirty lines and evict them in ~front
// order -> sequential writeback stream to DRAM (the fill kernel's regime).
// ---------------------------------------------------------------------------
__global__ __launch_bounds__(256) void gat_stream_full(
    const float* __restrict__ obs,      // [B*16,128]
    const float* __restrict__ pol,      // [B,16,8]
    const float* __restrict__ act,      // [B,16,8]
    const float* __restrict__ ws,
    float* __restrict__ out_obs)        // [B*16,16,136]
{
  const float* __restrict__ asrc = ws + WS_ASRC;
  const float* __restrict__ adst = ws + WS_ADST;
  const f32x4* __restrict__ sumz4 = (const f32x4*)(ws + WS_SUMZ);
  const f32x4* __restrict__ obs4 = (const f32x4*)obs;
  const f32x4* __restrict__ pol4 = (const f32x4*)pol;
  const f32x4* __restrict__ act4 = (const f32x4*)act;

  const unsigned total = B_SZ * 256u * 34u;            // 35,651,584
  const unsigned stride = gridDim.x * blockDim.x;      // 524,288 -> 68 iters
  for (unsigned idx = blockIdx.x * blockDim.x + threadIdx.x;
       idx < total; idx += stride) {
    const unsigned r  = idx / 34u;         // magic-mul div
    const unsigned d4 = idx - r * 34u;
    const unsigned bk = ((r >> 8) << 4) | (r & 15u);        // b*16 + k
    f32x4 val;
    if (d4 < 32u) {
      val = obs4[(size_t)bk * 32 + d4];
    } else {
      const unsigned t  = d4 - 32u;                         // 0 or 1
      const unsigned bi = ((r >> 8) << 4) | ((r >> 4) & 15u); // b*16 + i
      float e = asrc[bk] + adst[bi];
      e = (e >= 0.f) ? e : 0.01f * e;
      const float wv = 1.f / (1.f + expf(-e));
      const f32x4 pv = pol4[bk * 2 + t];
      const f32x4 av = act4[bk * 2 + t];
      const f32x4 sv = sumz4[bi * 2 + t];
      val = (sv - (wv * av + (1.f - wv) * pv) + pv) * 0.0625f;
    }
    ((f32x4*)out_obs)[idx] = val;          // PLAIN store -> L2 write-combining
  }
}

// ---------------------------------------------------------------------------
extern "C" void kernel_launch(void* const* d_in, const int* in_sizes, int n_in,
                              void* d_out, int out_size, void* d_ws, size_t ws_size,
                              hipStream_t stream) {
  const float* h      = (const float*)d_in[0];
  const float* pol    = (const float*)d_in[1];
  const float* act    = (const float*)d_in[2];
  const float* obs    = (const float*)d_in[3];
  const float* W_fc   = (const float*)d_in[4];
  const float* W_attn = (const float*)d_in[5];

  float* out = (float*)d_out;
  float* out_w = out + (size_t)B_SZ * N_SZ * N_SZ * ROW_OUT;  // 142,606,336
  float* ws = (float*)d_ws;   // needs 2.62 MB (verified available in R10)

  gat_compute<<<B_SZ, 256, 0, stream>>>(h, pol, act, W_fc, W_attn, ws, out_w);
  gat_stream_full<<<2048, 256, 0, stream>>>(obs, pol, act, ws, out);
}

// Round 13
// 139.738 us; speedup vs baseline: 1.7872x; 1.7872x over previous
//
#include <hip/hip_runtime.h>
#include <math.h>

// Sizes from the reference
#define B_SZ 4096
#define N_SZ 16
#define A_SZ 8
#define IN_DIM 128
#define OUT_DIM 128
#define D_OBS 128
#define ROW_OUT (D_OBS + A_SZ)   // 136

// Native clang vector (required by __builtin_nontemporal_*; HIP float4 is a struct)
typedef float f32x4 __attribute__((ext_vector_type(4)));

// ---------------------------------------------------------------------------
// Kernel 1: fold W_attn into W_fc.
//   v_src[i] = sum_o W_fc[o,i] * W_attn[0,o]
//   v_dst[i] = sum_o W_fc[o,i] * W_attn[0,128+o]
// 1 block, 256 threads, split-K by 2 to cut latency of the serial dispatch.
// ---------------------------------------------------------------------------
__global__ __launch_bounds__(256) void prep_v(const float* __restrict__ W_fc,
                                              const float* __restrict__ W_attn,
                                              float* __restrict__ v) {
  __shared__ float part[2][2][128];  // [half][src/dst][i]
  const int i = threadIdx.x & 127;
  const int half = threadIdx.x >> 7;   // 0: o in [0,64), 1: o in [64,128)
  float s = 0.f, d = 0.f;
  #pragma unroll 8
  for (int oo = 0; oo < 64; ++oo) {
    const int o = half * 64 + oo;
    const float w = W_fc[o * IN_DIM + i];
    s += w * W_attn[o];
    d += w * W_attn[OUT_DIM + o];
  }
  part[half][0][i] = s;
  part[half][1][i] = d;
  __syncthreads();
  if (half == 0) {
    v[i]          = part[0][0][i] + part[1][0][i];
    v[IN_DIM + i] = part[0][1][i] + part[1][1][i];
  }
}

// ---------------------------------------------------------------------------
// Kernel 2: one block per batch element b. 256 threads (4 waves).
// All global traffic is touch-once -> non-temporal loads/stores throughout.
// ---------------------------------------------------------------------------
__global__ __launch_bounds__(256) void gat_main(
    const float* __restrict__ h,        // [B,16,128]
    const float* __restrict__ pol,      // [B,16,8]
    const float* __restrict__ act,      // [B,16,8]
    const float* __restrict__ obs,      // [B*16,128]
    const float* __restrict__ v,        // [256] (v_src | v_dst)
    float* __restrict__ out_obs,        // [B*16,16,136]
    float* __restrict__ out_w)          // [B*16,16,1]
{
  const int b = blockIdx.x;
  const int tid = threadIdx.x;

  __shared__ float a_src_sm[16];
  __shared__ float a_dst_sm[16];
  __shared__ float w_sm[256];        // [i][j]
  __shared__ float pol_sm[128];      // [j][a]
  __shared__ float act_sm[128];
  __shared__ float sumz_sm[128];     // [i][a]
  __shared__ float outz_sm[2048];    // [i][k][a]
  __shared__ float obs_sm[2048];     // [k][d]

  // --- stage obs tile (16x128 = 512 x 16B), streaming loads ---
  {
    const f32x4* op = (const f32x4*)(obs + (size_t)b * (N_SZ * D_OBS));
    f32x4* od = (f32x4*)obs_sm;
    od[tid]       = __builtin_nontemporal_load(&op[tid]);
    od[tid + 256] = __builtin_nontemporal_load(&op[tid + 256]);
  }
  // --- stage policies / actions (128 floats each) ---
  if (tid < 128) {
    pol_sm[tid] = __builtin_nontemporal_load(&pol[(size_t)b * (N_SZ * A_SZ) + tid]);
    act_sm[tid] = __builtin_nontemporal_load(&act[(size_t)b * (N_SZ * A_SZ) + tid]);
  }

  // --- phase 1: a_src/a_dst. 16 lanes per row, 8 elems per lane. ---
  {
    const int n = tid >> 4;       // row 0..15
    const int l = tid & 15;       // lane-in-row
    const f32x4* hp = (const f32x4*)(h + (size_t)b * (N_SZ * IN_DIM));
    const f32x4 h0 = __builtin_nontemporal_load(&hp[tid * 2]);
    const f32x4 h1 = __builtin_nontemporal_load(&hp[tid * 2 + 1]);
    const f32x4* vs = (const f32x4*)v;
    const f32x4* vd = (const f32x4*)(v + IN_DIM);
    const f32x4 s0 = vs[l * 2], s1 = vs[l * 2 + 1];   // v: hot, keep cached
    const f32x4 d0 = vd[l * 2], d1 = vd[l * 2 + 1];
    float s = h0.x * s0.x + h0.y * s0.y + h0.z * s0.z + h0.w * s0.w
            + h1.x * s1.x + h1.y * s1.y + h1.z * s1.z + h1.w * s1.w;
    float d = h0.x * d0.x + h0.y * d0.y + h0.z * d0.z + h0.w * d0.w
            + h1.x * d1.x + h1.y * d1.y + h1.z * d1.z + h1.w * d1.w;
    for (int m = 8; m >= 1; m >>= 1) {
      s += __shfl_xor(s, m, 16);
      d += __shfl_xor(d, m, 16);
    }
    if (l == 0) {
      a_src_sm[n] = s;
      a_dst_sm[n] = d;
    }
  }
  __syncthreads();

  // --- phase 2: w[i][j] = sigmoid(leaky_relu(a_src[j] + a_dst[i], 0.01)) ---
  {
    const int i = tid >> 4, j = tid & 15;
    float e = a_src_sm[j] + a_dst_sm[i];
    e = (e >= 0.f) ? e : 0.01f * e;
    const float wv = 1.f / (1.f + expf(-e));
    w_sm[tid] = wv;
    __builtin_nontemporal_store(wv, &out_w[(size_t)b * 256 + tid]);  // output 1
  }
  __syncthreads();

  // --- phase 3a: sum_z[i][a] = sum_j (w[i][j]*act[j][a] + (1-w)*pol[j][a]) ---
  if (tid < 128) {
    const int i = tid >> 3, a = tid & 7;
    float s = 0.f;
    for (int j = 0; j < N_SZ; ++j) {
      const float wv = w_sm[i * 16 + j];
      s += wv * act_sm[j * 8 + a] + (1.f - wv) * pol_sm[j * 8 + a];
    }
    sumz_sm[tid] = s;
  }
  __syncthreads();

  // --- phase 3b: out_z[i][k][a] = (sum_z[i][a] - zg[i][k][a] + pol[k][a])/16 ---
  {
    const int i = tid >> 4, k = tid & 15;
    const float wv = w_sm[tid];   // w[i][k]
    for (int a = 0; a < A_SZ; ++a) {
      const float zg = wv * act_sm[k * 8 + a] + (1.f - wv) * pol_sm[k * 8 + a];
      outz_sm[tid * 8 + a] =
          (sumz_sm[i * 8 + a] - zg + pol_sm[k * 8 + a]) * 0.0625f;
    }
  }
  __syncthreads();

  // --- phase 4: write 256 rows x 34 x 16B (fully contiguous per block) ---
  // flat 16B idx: r = idx/34, d4 = idx%34.
  // d4 < 32  -> obs_sm[k][d4*4 ..] ; d4 >= 32 -> outz_sm[r*8 + (d4-32)*4 ..]
  float* ob = out_obs + (size_t)b * (256 * ROW_OUT);
  const f32x4* obs4 = (const f32x4*)obs_sm;
  #pragma unroll 2
  for (int idx = tid; idx < 256 * 34; idx += 256) {
    const int r = idx / 34;
    const int d4 = idx - r * 34;
    f32x4 o4;
    if (d4 < 32) {
      const int k = r & 15;
      o4 = obs4[k * 32 + d4];
    } else {
      o4 = *(const f32x4*)(outz_sm + r * 8 + (d4 - 32) * 4);
    }
    __builtin_nontemporal_store(o4, (f32x4*)(ob + (size_t)idx * 4));
  }
}

// ---------------------------------------------------------------------------
extern "C" void kernel_launch(void* const* d_in, const int* in_sizes, int n_in,
                              void* d_out, int out_size, void* d_ws, size_t ws_size,
                              hipStream_t stream) {
  const float* h      = (const float*)d_in[0];
  const float* pol    = (const float*)d_in[1];
  const float* act    = (const float*)d_in[2];
  const float* obs    = (const float*)d_in[3];
  const float* W_fc   = (const float*)d_in[4];
  const float* W_attn = (const float*)d_in[5];

  float* out = (float*)d_out;
  float* out_w = out + (size_t)B_SZ * N_SZ * N_SZ * ROW_OUT;  // 142,606,336
  float* v = (float*)d_ws;  // 256 floats

  prep_v<<<1, 256, 0, stream>>>(W_fc, W_attn, v);
  gat_main<<<B_SZ, 256, 0, stream>>>(h, pol, act, obs, v, out, out_w);
}

// Round 14
// 139.712 us; speedup vs baseline: 1.7876x; 1.0002x over previous
//
#include <hip/hip_runtime.h>
#include <math.h>

// Sizes from the reference
#define B_SZ 4096
#define N_SZ 16
#define A_SZ 8
#define IN_DIM 128
#define OUT_DIM 128
#define D_OBS 128
#define ROW_OUT (D_OBS + A_SZ)   // 136

// Native clang vector (required by __builtin_nontemporal_*; HIP float4 is a struct)
typedef float f32x4 __attribute__((ext_vector_type(4)));

// ---------------------------------------------------------------------------
// Single fused kernel: one block per batch element b. 256 threads (4 waves).
// The W_attn@W_fc fold (v) is computed in-block from the L2-resident 64 KB
// W_fc (eliminates the serial 1-block prep dispatch + launch gap, ~5% of
// total). All global traffic is touch-once -> non-temporal loads/stores.
// ---------------------------------------------------------------------------
__global__ __launch_bounds__(256) void gat_main(
    const float* __restrict__ h,        // [B,16,128]
    const float* __restrict__ pol,      // [B,16,8]
    const float* __restrict__ act,      // [B,16,8]
    const float* __restrict__ obs,      // [B*16,128]
    const float* __restrict__ W_fc,     // [128,128]
    const float* __restrict__ W_attn,   // [1,256]
    float* __restrict__ out_obs,        // [B*16,16,136]
    float* __restrict__ out_w)          // [B*16,16,1]
{
  const int b = blockIdx.x;
  const int tid = threadIdx.x;

  __shared__ float vsm[256];         // v_src[128] | v_dst[128]
  __shared__ float a_src_sm[16];
  __shared__ float a_dst_sm[16];
  __shared__ float w_sm[256];        // [i][j]
  __shared__ float pol_sm[128];      // [j][a]
  __shared__ float act_sm[128];
  __shared__ float sumz_sm[128];     // [i][a]
  __shared__ float outz_sm[2048];    // [i][k][a]
  __shared__ float obs_sm[2048];     // [k][d]

  // --- stage obs tile (16x128 = 512 x 16B), streaming loads (issue first so
  //     they are in flight under the vsm compute) ---
  {
    const f32x4* op = (const f32x4*)(obs + (size_t)b * (N_SZ * D_OBS));
    f32x4* od = (f32x4*)obs_sm;
    od[tid]       = __builtin_nontemporal_load(&op[tid]);
    od[tid + 256] = __builtin_nontemporal_load(&op[tid + 256]);
  }
  // --- stage policies / actions (128 floats each) ---
  if (tid < 128) {
    pol_sm[tid] = __builtin_nontemporal_load(&pol[(size_t)b * (N_SZ * A_SZ) + tid]);
    act_sm[tid] = __builtin_nontemporal_load(&act[(size_t)b * (N_SZ * A_SZ) + tid]);
  }

  // --- fold: vsm[tid] = sum_o W_fc[o, tid&127] * W_attn[(tid>>7)*128 + o] ---
  //     (W_fc is 64 KB -> L2/L3-hot across all 4096 blocks; coalesced loads)
  {
    const int col = tid & 127;
    const float* wa = W_attn + ((tid >> 7) << 7);
    float acc = 0.f;
    #pragma unroll 8
    for (int o = 0; o < OUT_DIM; ++o)
      acc += W_fc[o * IN_DIM + col] * wa[o];
    vsm[tid] = acc;
  }
  __syncthreads();   // vsm ready

  // --- phase 1: a_src/a_dst. 16 lanes per row, 8 elems per lane. ---
  {
    const int n = tid >> 4;       // row 0..15
    const int l = tid & 15;       // lane-in-row
    const f32x4* hp = (const f32x4*)(h + (size_t)b * (N_SZ * IN_DIM));
    const f32x4 h0 = __builtin_nontemporal_load(&hp[tid * 2]);
    const f32x4 h1 = __builtin_nontemporal_load(&hp[tid * 2 + 1]);
    const f32x4* vs = (const f32x4*)vsm;
    const f32x4* vd = (const f32x4*)(vsm + IN_DIM);
    const f32x4 s0 = vs[l * 2], s1 = vs[l * 2 + 1];
    const f32x4 d0 = vd[l * 2], d1 = vd[l * 2 + 1];
    float s = h0.x * s0.x + h0.y * s0.y + h0.z * s0.z + h0.w * s0.w
            + h1.x * s1.x + h1.y * s1.y + h1.z * s1.z + h1.w * s1.w;
    float d = h0.x * d0.x + h0.y * d0.y + h0.z * d0.z + h0.w * d0.w
            + h1.x * d1.x + h1.y * d1.y + h1.z * d1.z + h1.w * d1.w;
    for (int m = 8; m >= 1; m >>= 1) {
      s += __shfl_xor(s, m, 16);
      d += __shfl_xor(d, m, 16);
    }
    if (l == 0) {
      a_src_sm[n] = s;
      a_dst_sm[n] = d;
    }
  }
  __syncthreads();

  // --- phase 2: w[i][j] = sigmoid(leaky_relu(a_src[j] + a_dst[i], 0.01)) ---
  {
    const int i = tid >> 4, j = tid & 15;
    float e = a_src_sm[j] + a_dst_sm[i];
    e = (e >= 0.f) ? e : 0.01f * e;
    const float wv = 1.f / (1.f + expf(-e));
    w_sm[tid] = wv;
    __builtin_nontemporal_store(wv, &out_w[(size_t)b * 256 + tid]);  // output 1
  }
  __syncthreads();

  // --- phase 3a: sum_z[i][a] = sum_j (w[i][j]*act[j][a] + (1-w)*pol[j][a]) ---
  if (tid < 128) {
    const int i = tid >> 3, a = tid & 7;
    float s = 0.f;
    for (int j = 0; j < N_SZ; ++j) {
      const float wv = w_sm[i * 16 + j];
      s += wv * act_sm[j * 8 + a] + (1.f - wv) * pol_sm[j * 8 + a];
    }
    sumz_sm[tid] = s;
  }
  __syncthreads();

  // --- phase 3b: out_z[i][k][a] = (sum_z[i][a] - zg[i][k][a] + pol[k][a])/16 ---
  {
    const int i = tid >> 4, k = tid & 15;
    const float wv = w_sm[tid];   // w[i][k]
    for (int a = 0; a < A_SZ; ++a) {
      const float zg = wv * act_sm[k * 8 + a] + (1.f - wv) * pol_sm[k * 8 + a];
      outz_sm[tid * 8 + a] =
          (sumz_sm[i * 8 + a] - zg + pol_sm[k * 8 + a]) * 0.0625f;
    }
  }
  __syncthreads();

  // --- phase 4: write 256 rows x 34 x 16B (fully contiguous per block) ---
  // flat 16B idx: r = idx/34, d4 = idx%34.
  // d4 < 32  -> obs_sm[k][d4*4 ..] ; d4 >= 32 -> outz_sm[r*8 + (d4-32)*4 ..]
  float* ob = out_obs + (size_t)b * (256 * ROW_OUT);
  const f32x4* obs4 = (const f32x4*)obs_sm;
  #pragma unroll 2
  for (int idx = tid; idx < 256 * 34; idx += 256) {
    const int r = idx / 34;
    const int d4 = idx - r * 34;
    f32x4 o4;
    if (d4 < 32) {
      const int k = r & 15;
      o4 = obs4[k * 32 + d4];
    } else {
      o4 = *(const f32x4*)(outz_sm + r * 8 + (d4 - 32) * 4);
    }
    __builtin_nontemporal_store(o4, (f32x4*)(ob + (size_t)idx * 4));
  }
}

// ---------------------------------------------------------------------------
extern "C" void kernel_launch(void* const* d_in, const int* in_sizes, int n_in,
                              void* d_out, int out_size, void* d_ws, size_t ws_size,
                              hipStream_t stream) {
  const float* h      = (const float*)d_in[0];
  const float* pol    = (const float*)d_in[1];
  const float* act    = (const float*)d_in[2];
  const float* obs    = (const float*)d_in[3];
  const float* W_fc   = (const float*)d_in[4];
  const float* W_attn = (const float*)d_in[5];

  float* out = (float*)d_out;
  float* out_w = out + (size_t)B_SZ * N_SZ * N_SZ * ROW_OUT;  // 142,606,336

  gat_main<<<B_SZ, 256, 0, stream>>>(h, pol, act, obs, W_fc, W_attn, out, out_w);
}